// Round 6
// baseline (96.603 us; speedup 1.0000x reference)
//
#include <hip/hip_runtime.h>
#include <math.h>

typedef unsigned short u16;
typedef __bf16 bf16x8 __attribute__((ext_vector_type(8)));
typedef float f32x4 __attribute__((ext_vector_type(4)));

#define B_ 32
#define W_ 512
#define H_ 768
#define HH_ 384
#define E_ 128
#define R_ 1024
#define BE_ (B_*E_)     /* 4096 */
#define K1_ (2*H_)      /* 1536 */
#define BKK 64

__device__ __forceinline__ u16 f2bf(float f) {
  unsigned u = __float_as_uint(f);
  u = (u + 0x7fffu + ((u >> 16) & 1u)) >> 16;   // RNE
  return (u16)u;
}
__device__ __forceinline__ float bf2f(u16 u) {
  return __uint_as_float(((unsigned)u) << 16);
}

__device__ __forceinline__ void gload_lds16(const void* g, void* l) {
  __builtin_amdgcn_global_load_lds(
      (__attribute__((address_space(1))) void*)(g),
      (__attribute__((address_space(3))) void*)(l), 16, 0, 0);
}

// ---------------------------------------------------------------------------
// Fused prep: (A) weight->bf16, (B) P table P[l,n]=emb[l].W1[n,768:]+b1[n],
// (C) entity token gather to bf16.
// ---------------------------------------------------------------------------
#define NBLK_W 2017
#define NBLK_P 1152
#define NBLK_X 4096

__global__ __launch_bounds__(256) void prep_all(
    const float* __restrict__ Wh1, const float* __restrict__ Wt1,
    const float* __restrict__ Wh2, const float* __restrict__ Wt2,
    const float* __restrict__ Wbil,
    const float* __restrict__ bh1, const float* __restrict__ bt1,
    const float* __restrict__ bh2, const float* __restrict__ bt2,
    const float* __restrict__ emb,
    const float* __restrict__ hs, const int* __restrict__ ent_start,
    u16* __restrict__ W1c, u16* __restrict__ W2c, u16* __restrict__ Wb,
    float* __restrict__ b2cat, float* __restrict__ P, u16* __restrict__ X)
{
  const int blk = blockIdx.x;
  const int tid = threadIdx.x;

  if (blk < NBLK_W) {
    const int i = blk * 256 + tid;
    const int SW1 = 294912;              // W1c: 1536 rows x 768 cols /4
    const int SW2 = SW1 + 147456;        // W2c: 768x768 /4
    const int SWB = SW2 + 73728;         // Wb:  768x384 /4
    const int SB2 = SWB + 192;           // b2cat: 768 /4
    if (i < SW1) {
      int row = i / 192, c = i % 192;
      const float4* src = (const float4*)((row < 768)
          ? (Wh1 + (size_t)row * K1_) : (Wt1 + (size_t)(row - 768) * K1_));
      float4 v = src[c];
      ushort4 o; o.x = f2bf(v.x); o.y = f2bf(v.y); o.z = f2bf(v.z); o.w = f2bf(v.w);
      ((ushort4*)W1c)[i] = o;
    } else if (i < SW2) {
      int j = i - SW1;
      float4 v = (j < 73728) ? ((const float4*)Wh2)[j]
                             : ((const float4*)Wt2)[j - 73728];
      ushort4 o; o.x = f2bf(v.x); o.y = f2bf(v.y); o.z = f2bf(v.z); o.w = f2bf(v.w);
      ((ushort4*)W2c)[j] = o;
    } else if (i < SWB) {
      int j = i - SW2;
      float4 v = ((const float4*)Wbil)[j];
      ushort4 o; o.x = f2bf(v.x); o.y = f2bf(v.y); o.z = f2bf(v.z); o.w = f2bf(v.w);
      ((ushort4*)Wb)[j] = o;
    } else if (i < SB2) {
      int j = i - SWB;
      ((float4*)b2cat)[j] = (j < 96) ? ((const float4*)bh2)[j]
                                     : ((const float4*)bt2)[j - 96];
    }
  } else if (blk < NBLK_W + NBLK_P) {
    const int w = (blk - NBLK_W) * 4 + (tid >> 6);
    const int lane = tid & 63;
    const int l = w / K1_;
    const int n = w - l * K1_;
    const float* wrow = (n < 768) ? (Wh1 + (size_t)n * K1_ + 768)
                                  : (Wt1 + (size_t)(n - 768) * K1_ + 768);
    const float  bb   = (n < 768) ? bh1[n] : bt1[n - 768];
    const float* ev = emb + (size_t)l * H_;
    float s = 0.f;
#pragma unroll
    for (int t = 0; t < 12; ++t) {
      int d = lane + 64 * t;
      s += ev[d] * wrow[d];
    }
#pragma unroll
    for (int off = 32; off; off >>= 1) s += __shfl_down(s, off);
    if (lane == 0) P[(size_t)l * K1_ + n] = s + bb;
  } else {
    const int be = blk - (NBLK_W + NBLK_P);
    if (tid < 192) {
      int b = be >> 7;
      int start = ent_start[be];
      const float4* s0 = (const float4*)(hs + ((size_t)b * W_ + start) * H_);
      float4 v = s0[tid];
      ushort4 o; o.x = f2bf(v.x); o.y = f2bf(v.y); o.z = f2bf(v.z); o.w = f2bf(v.w);
      ((ushort4*)(X + (size_t)be * H_))[tid] = o;
    }
  }
}

// ---------------------------------------------------------------------------
// Templated bf16 MFMA GEMM, double-buffered 2-phase, TBMxTBN tiles, 4 waves
// (2x2 wave grid, TBM/2 x TBN/2 each). Linear LDS + pre-swizzled source.
// 1D grid with bijective XCD-chunked swizzle over ngemm blocks; blocks past
// ngemm run the per-entity W_lin dot tail (and zero out[0]).
// ---------------------------------------------------------------------------
template<int TBM, int TBN, int MINB>
__global__ __launch_bounds__(256, MINB) void gemm_t(
    const u16* __restrict__ A, int lda,
    const u16* __restrict__ Wt,              // [N][K] row-major
    const float* __restrict__ bias,
    u16* __restrict__ C, int ldc, int K,
    int do_relu, int half_n, int aoff,
    const float* __restrict__ rowBias,       // P [3][ldP] or null
    const int* __restrict__ rowLabel, int ldP,
    int nbx, int ngemm,
    const u16* __restrict__ linSrc, const float* __restrict__ W_lin,
    float* __restrict__ linHT, float* __restrict__ out)
{
  constexpr int FM = TBM / 32;
  constexpr int FN = TBN / 32;
  constexpr int UNITS = (TBM + TBN) / 8;   // 1KB staging units per buffer
  constexpr int UPW = UNITS / 4;
  constexpr int BUFB = (TBM + TBN) * 128;

  __shared__ char smem[2 * BUFB];

  const int tid  = threadIdx.x;
  const int wid  = tid >> 6;
  const int lane = tid & 63;

  if ((int)blockIdx.x >= ngemm) {
    // ---- lin_parts tail: linHT[be] = {h.Wl0, h.Wl1, t.Wl0t, t.Wl1t} ----
    if ((int)blockIdx.x == ngemm && tid == 0) out[0] = 0.f;
    const int nblk  = gridDim.x - ngemm;
    const int wave  = ((int)blockIdx.x - ngemm) * 4 + wid;
    const int nwave = nblk * 4;
    for (int be = wave; be < BE_; be += nwave) {
      const ushort4* src = (const ushort4*)(linSrc + (size_t)be * 768);
      float s0 = 0.f, s1 = 0.f, s2 = 0.f, s3 = 0.f;
#pragma unroll
      for (int rd = 0; rd < 3; ++rd) {
        const int idx4 = rd * 64 + lane;
        const int c = idx4 * 4;
        ushort4 v4 = src[idx4];
        float4 w0 = *(const float4*)(W_lin + c);
        float4 w1 = *(const float4*)(W_lin + 768 + c);
        float d0 = bf2f(v4.x)*w0.x + bf2f(v4.y)*w0.y + bf2f(v4.z)*w0.z + bf2f(v4.w)*w0.w;
        float d1 = bf2f(v4.x)*w1.x + bf2f(v4.y)*w1.y + bf2f(v4.z)*w1.z + bf2f(v4.w)*w1.w;
        if (c < 384) { s0 += d0; s1 += d1; }
        else         { s2 += d0; s3 += d1; }
      }
#pragma unroll
      for (int off = 32; off; off >>= 1) {
        s0 += __shfl_down(s0, off);
        s1 += __shfl_down(s1, off);
        s2 += __shfl_down(s2, off);
        s3 += __shfl_down(s3, off);
      }
      if (lane == 0) {
        float4 v = {s0, s1, s2, s3};
        *(float4*)(linHT + (size_t)be * 4) = v;
      }
    }
    return;
  }

  // bijective XCD-chunked swizzle over ngemm
  const int q = ngemm >> 3, r = ngemm & 7;
  const int xcd = blockIdx.x & 7, idx = blockIdx.x >> 3;
  const int wgid = (xcd < r ? xcd * (q + 1) : r * (q + 1) + (xcd - r) * q) + idx;
  const int bn = (wgid % nbx) * TBN;
  const int bm = (wgid / nbx) * TBM;

  const int a0 = (half_n && bn >= half_n) ? aoff : 0;
  const int srow = lane >> 3;
  const int sk8  = (lane & 7) ^ srow;

  auto stage = [&](int buf, int k0) {
    char* base = smem + buf * BUFB;
#pragma unroll
    for (int i = 0; i < UPW; ++i) {
      const int u = wid * UPW + i;
      if (u < TBM / 8) {
        const int row = bm + u * 8 + srow;
        gload_lds16(A + (size_t)row * lda + a0 + k0 + 8 * sk8, base + u * 1024);
      } else {
        const int row = bn + (u - TBM / 8) * 8 + srow;
        gload_lds16(Wt + (size_t)row * K + k0 + 8 * sk8, base + u * 1024);
      }
    }
  };

  const int wm = (wid >> 1) * (TBM / 2);
  const int wn = (wid & 1) * (TBN / 2);
  const int frow = lane & 15;
  const int fk8  = lane >> 4;

  f32x4 acc[FM][FN] = {};

  const int nt = K / BKK;
  stage(0, 0);
  asm volatile("s_waitcnt vmcnt(0)" ::: "memory");
  __syncthreads();

  for (int t = 0; t < nt; ++t) {
    const int cur = t & 1;
    if (t + 1 < nt) stage(cur ^ 1, (t + 1) * BKK);

    char* As = smem + cur * BUFB;
    char* Bs = As + TBM * 128;
#pragma unroll
    for (int kh = 0; kh < 2; ++kh) {
      bf16x8 a[FM], b[FN];
#pragma unroll
      for (int m = 0; m < FM; ++m) {
        const int row  = wm + m*16 + frow;
        const int slot = (kh*4 + fk8) ^ (row & 7);
        a[m] = *(const bf16x8*)(As + row*128 + slot*16);
      }
#pragma unroll
      for (int n = 0; n < FN; ++n) {
        const int row  = wn + n*16 + frow;
        const int slot = (kh*4 + fk8) ^ (row & 7);
        b[n] = *(const bf16x8*)(Bs + row*128 + slot*16);
      }
#pragma unroll
      for (int m = 0; m < FM; ++m)
#pragma unroll
        for (int n = 0; n < FN; ++n)
          acc[m][n] = __builtin_amdgcn_mfma_f32_16x16x32_bf16(
              a[m], b[n], acc[m][n], 0, 0, 0);
    }

    if (t + 1 < nt) {
      asm volatile("s_waitcnt vmcnt(0)" ::: "memory");
      __syncthreads();
    }
  }

  int lbl[FM][4];
  if (rowLabel) {
#pragma unroll
    for (int m = 0; m < FM; ++m)
#pragma unroll
      for (int r = 0; r < 4; ++r)
        lbl[m][r] = rowLabel[bm + wm + m*16 + fk8*4 + r];
  }

#pragma unroll
  for (int n = 0; n < FN; ++n) {
    const int col = bn + wn + n*16 + frow;
    const float bv = bias ? bias[col] : 0.f;
    float p0 = 0.f, p1 = 0.f, p2 = 0.f;
    if (rowLabel) {
      p0 = rowBias[col];
      p1 = rowBias[ldP + col];
      p2 = rowBias[2*ldP + col];
    }
#pragma unroll
    for (int m = 0; m < FM; ++m) {
#pragma unroll
      for (int r = 0; r < 4; ++r) {
        const int row = bm + wm + m*16 + fk8*4 + r;
        float v = acc[m][n][r] + bv;
        if (rowLabel) {
          int l = lbl[m][r];
          v += (l == 0) ? p0 : ((l == 1) ? p1 : p2);
        }
        if (do_relu) v = fmaxf(v, 0.f);
        C[(size_t)row * ldc + col] = f2bf(v);
      }
    }
  }
}

// ---------------------------------------------------------------------------
// Fused score-GEMM + CE. One block per (doc-half, e2-quarter): 64x64 S-tile
// kept in LDS; then the block scans its doc's 1024 relations, picks the ones
// landing in its tile, computes CE, one atomic per block. No S in HBM.
// grid = 256 (4 bn x 64 zz), 4 waves, K=384.
// ---------------------------------------------------------------------------
__global__ __launch_bounds__(256, 2) void gemm_S_ce(
    const u16* __restrict__ Hcat, const u16* __restrict__ U,
    const float* __restrict__ linHT, const float* __restrict__ b_lin,
    const int* __restrict__ rel_head, const int* __restrict__ rel_tail,
    const int* __restrict__ rel_label, float* __restrict__ out)
{
  __shared__ char smem[2 * 16384];
  __shared__ float Sl[64][65];
  __shared__ float red[4];

  // swizzle over 256 blocks (q=32, r=0)
  const int xcd = blockIdx.x & 7, idx = blockIdx.x >> 3;
  const int wgid = xcd * 32 + idx;
  const int bn = (wgid & 3) * 64;          // cols of [256]-wide (e2,o) space
  const int zz = wgid >> 2;
  const int z  = zz >> 1;
  const int bm = (zz & 1) * 64;            // e1 rows within doc

  const int tid  = threadIdx.x;
  const int wid  = tid >> 6;
  const int lane = tid & 63;
  const int srow = lane >> 3;
  const int sk8  = (lane & 7) ^ srow;

  auto stage = [&](int buf, int k0) {
    char* base = smem + buf * 16384;
#pragma unroll
    for (int i = 0; i < 4; ++i) {
      const int u = wid * 4 + i;
      if (u < 8) {
        const int row = z*128 + bm + u*8 + srow;
        gload_lds16(Hcat + (size_t)row * 768 + k0 + 8*sk8, base + u*1024);
      } else {
        const int row = bn + (u - 8)*8 + srow;
        gload_lds16(U + (size_t)z*98304 + (size_t)row * 384 + k0 + 8*sk8,
                    base + u*1024);
      }
    }
  };

  const int wm = (wid >> 1) * 32;
  const int wn = (wid & 1) * 32;
  const int frow = lane & 15;
  const int fk8  = lane >> 4;

  f32x4 acc[2][2] = {};

  stage(0, 0);
  asm volatile("s_waitcnt vmcnt(0)" ::: "memory");
  __syncthreads();

  for (int t = 0; t < 6; ++t) {
    const int cur = t & 1;
    if (t + 1 < 6) stage(cur ^ 1, (t + 1) * BKK);

    char* As = smem + cur * 16384;
    char* Bs = As + 8192;
#pragma unroll
    for (int kh = 0; kh < 2; ++kh) {
      bf16x8 a[2], b[2];
#pragma unroll
      for (int m = 0; m < 2; ++m) {
        const int row  = wm + m*16 + frow;
        const int slot = (kh*4 + fk8) ^ (row & 7);
        a[m] = *(const bf16x8*)(As + row*128 + slot*16);
      }
#pragma unroll
      for (int n = 0; n < 2; ++n) {
        const int row  = wn + n*16 + frow;
        const int slot = (kh*4 + fk8) ^ (row & 7);
        b[n] = *(const bf16x8*)(Bs + row*128 + slot*16);
      }
#pragma unroll
      for (int m = 0; m < 2; ++m)
#pragma unroll
        for (int n = 0; n < 2; ++n)
          acc[m][n] = __builtin_amdgcn_mfma_f32_16x16x32_bf16(
              a[m], b[n], acc[m][n], 0, 0, 0);
    }

    if (t + 1 < 6) {
      asm volatile("s_waitcnt vmcnt(0)" ::: "memory");
      __syncthreads();
    }
  }
  __syncthreads();   // all staging reads done before Sl reuse of LDS space

  // epilogue into LDS: o parity = frow&1 (bn, wn, n*16 even)
  const int o = frow & 1;
  const float blv = b_lin[o];
#pragma unroll
  for (int n = 0; n < 2; ++n) {
    const int lc = wn + n*16 + frow;
    const int e2 = (bn + lc) >> 1;
    const float lt = linHT[(size_t)(z*128 + e2) * 4 + 2 + o];
#pragma unroll
    for (int m = 0; m < 2; ++m) {
#pragma unroll
      for (int r = 0; r < 4; ++r) {
        const int lr = wm + m*16 + fk8*4 + r;
        const float lh = linHT[(size_t)(z*128 + bm + lr) * 4 + o];
        Sl[lr][lc] = acc[m][n][r] + lh + lt + blv;
      }
    }
  }
  __syncthreads();

  // CE over this tile's relations
  float nllsum = 0.f;
#pragma unroll
  for (int j = 0; j < 4; ++j) {
    const int i = z * 1024 + tid + 256 * j;
    const int rh = rel_head[i];
    const int rt = rel_tail[i];
    const int lab = rel_label[i];
    if ((unsigned)(rh - bm) < 64u && (unsigned)(rt*2 - bn) < 64u) {
      const float l0 = Sl[rh - bm][rt*2 - bn];
      const float l1 = Sl[rh - bm][rt*2 - bn + 1];
      const float mx = fmaxf(l0, l1);
      const float lse = mx + logf(expf(l0 - mx) + expf(l1 - mx));
      nllsum += lse - (lab == 0 ? l0 : l1);
    }
  }
#pragma unroll
  for (int off = 32; off; off >>= 1) nllsum += __shfl_down(nllsum, off);
  if (lane == 0) red[wid] = nllsum;
  __syncthreads();
  if (tid == 0)
    atomicAdd(out, (red[0] + red[1] + red[2] + red[3]) * (1.0f / R_));
}

// ---------------------------------------------------------------------------
extern "C" void kernel_launch(void* const* d_in, const int* in_sizes, int n_in,
                              void* d_out, int out_size, void* d_ws, size_t ws_size,
                              hipStream_t stream)
{
  const float* hs        = (const float*)d_in[0];
  const int*   rel_head  = (const int*)  d_in[1];
  const int*   rel_tail  = (const int*)  d_in[2];
  const int*   rel_label = (const int*)  d_in[3];
  const int*   ent_start = (const int*)  d_in[4];
  const int*   ent_label = (const int*)  d_in[6];
  const float* emb   = (const float*)d_in[7];
  const float* Wh1   = (const float*)d_in[8];
  const float* bh1   = (const float*)d_in[9];
  const float* Wh2   = (const float*)d_in[10];
  const float* bh2   = (const float*)d_in[11];
  const float* Wt1   = (const float*)d_in[12];
  const float* bt1   = (const float*)d_in[13];
  const float* Wt2   = (const float*)d_in[14];
  const float* bt2   = (const float*)d_in[15];
  const float* W_bil = (const float*)d_in[16];
  const float* W_lin = (const float*)d_in[17];
  const float* b_lin = (const float*)d_in[18];
  float* out = (float*)d_out;

  // workspace layout
  u16* X    = (u16*)d_ws;                 // 4096*768
  u16* H1   = X    + (size_t)BE_ * H_;    // 4096*1536
  u16* Hcat = H1   + (size_t)BE_ * K1_;   // 4096*768
  u16* U    = Hcat + (size_t)BE_ * H_;    // 4096*768
  u16* W1c  = U    + (size_t)BE_ * H_;    // 1536*768
  u16* W2c  = W1c  + (size_t)K1_ * H_;    // 768*768
  u16* Wb   = W2c  + (size_t)H_ * H_;     // 768*384
  float* b2cat = (float*)(Wb + (size_t)H_ * HH_);  // 768
  float* P     = b2cat + H_;                       // 3*1536
  float* linHT = P + 3*K1_;                        // 4096*4

  // 1) fused prep
  prep_all<<<dim3(NBLK_W + NBLK_P + NBLK_X), dim3(256), 0, stream>>>(
      Wh1, Wt1, Wh2, Wt2, W_bil, bh1, bt1, bh2, bt2, emb,
      hs, ent_start, W1c, W2c, Wb, b2cat, P, X);

  // 2) layer-1 GEMM: H1 = relu(X @ W1c^T + P[label]) [4096,1536], K=768
  //    64x128 tiles -> 12 x 64 = 768 blocks = 3/CU exactly
  gemm_t<64,128,3><<<dim3(768), dim3(256), 0, stream>>>(
      X, H_, W1c, (const float*)nullptr, H1, K1_, H_, 1, 0, 0,
      P, ent_label, K1_, 12, 768,
      (const u16*)nullptr, (const float*)nullptr, (float*)nullptr, (float*)nullptr);

  // 3) layer-2 fused GEMM: Hcat = relu([H1h@Wh2^T ; H1t@Wt2^T] + b2cat)
  //    [4096,768], K=768; 64x64 tiles -> 12 x 64 = 768 blocks
  gemm_t<64,64,4><<<dim3(768), dim3(256), 0, stream>>>(
      H1, K1_, W2c, b2cat, Hcat, H_, H_, 1, HH_, H_,
      (const float*)nullptr, (const int*)nullptr, 0, 12, 768,
      (const u16*)nullptr, (const float*)nullptr, (float*)nullptr, (float*)nullptr);

  // 4) bilinear hoist + lin_parts tail + out zero:
  //    U = Ht @ Wbil^T [4096,768], K=384; 768 GEMM blocks + 16 lin blocks
  gemm_t<64,64,4><<<dim3(768 + 16), dim3(256), 0, stream>>>(
      Hcat + HH_, H_, Wb, (const float*)nullptr, U, H_, HH_, 0, 0, 0,
      (const float*)nullptr, (const int*)nullptr, 0, 12, 768,
      Hcat, W_lin, linHT, out);

  // 5) fused score GEMM + CE (no S materialization)
  gemm_S_ce<<<dim3(256), dim3(256), 0, stream>>>(
      Hcat, U, linHT, b_lin, rel_head, rel_tail, rel_label, out);
}

// Round 7
// 76.597 us; speedup vs baseline: 1.2612x; 1.2612x over previous
//
#include <hip/hip_runtime.h>
#include <math.h>

typedef unsigned short u16;
typedef __bf16 bf16x8 __attribute__((ext_vector_type(8)));
typedef float f32x4 __attribute__((ext_vector_type(4)));

#define B_ 32
#define W_ 512
#define H_ 768
#define HH_ 384
#define E_ 128
#define R_ 1024
#define BE_ (B_*E_)     /* 4096 */
#define K1_ (2*H_)      /* 1536 */
#define BKK 64

__device__ __forceinline__ u16 f2bf(float f) {
  unsigned u = __float_as_uint(f);
  u = (u + 0x7fffu + ((u >> 16) & 1u)) >> 16;   // RNE
  return (u16)u;
}
__device__ __forceinline__ float bf2f(u16 u) {
  return __uint_as_float(((unsigned)u) << 16);
}

__device__ __forceinline__ void gload_lds16(const void* g, void* l) {
  __builtin_amdgcn_global_load_lds(
      (__attribute__((address_space(1))) void*)(g),
      (__attribute__((address_space(3))) void*)(l), 16, 0, 0);
}

// bijective XCD-chunked block swizzle (m204)
__device__ __forceinline__ void xcd_swizzle(int& bx, int& by) {
  const int nwg = gridDim.x * gridDim.y;
  int orig = blockIdx.y * gridDim.x + blockIdx.x;
  int q = nwg >> 3, r = nwg & 7;
  int xcd = orig & 7, idx = orig >> 3;
  int wgid = (xcd < r ? xcd * (q + 1) : r * (q + 1) + (xcd - r) * q) + idx;
  bx = wgid % gridDim.x;
  by = wgid / gridDim.x;
}

// ---------------------------------------------------------------------------
// Fused prep: (A) weight->bf16, (B) P table P[l,n]=emb[l].W1[n,768:]+b1[n],
// (C) entity token gather to bf16.
// ---------------------------------------------------------------------------
#define NBLK_W 2017
#define NBLK_P 1152
#define NBLK_X 4096

__global__ __launch_bounds__(256) void prep_all(
    const float* __restrict__ Wh1, const float* __restrict__ Wt1,
    const float* __restrict__ Wh2, const float* __restrict__ Wt2,
    const float* __restrict__ Wbil,
    const float* __restrict__ bh1, const float* __restrict__ bt1,
    const float* __restrict__ bh2, const float* __restrict__ bt2,
    const float* __restrict__ emb,
    const float* __restrict__ hs, const int* __restrict__ ent_start,
    u16* __restrict__ W1c, u16* __restrict__ W2c, u16* __restrict__ Wb,
    float* __restrict__ b2cat, float* __restrict__ P, u16* __restrict__ X)
{
  const int blk = blockIdx.x;
  const int tid = threadIdx.x;

  if (blk < NBLK_W) {
    const int i = blk * 256 + tid;
    const int SW1 = 294912;              // W1c: 1536 rows x 768 cols /4
    const int SW2 = SW1 + 147456;        // W2c: 768x768 /4
    const int SWB = SW2 + 73728;         // Wb:  768x384 /4
    const int SB2 = SWB + 192;           // b2cat: 768 /4
    if (i < SW1) {
      int row = i / 192, c = i % 192;
      const float4* src = (const float4*)((row < 768)
          ? (Wh1 + (size_t)row * K1_) : (Wt1 + (size_t)(row - 768) * K1_));
      float4 v = src[c];
      ushort4 o; o.x = f2bf(v.x); o.y = f2bf(v.y); o.z = f2bf(v.z); o.w = f2bf(v.w);
      ((ushort4*)W1c)[i] = o;
    } else if (i < SW2) {
      int j = i - SW1;
      float4 v = (j < 73728) ? ((const float4*)Wh2)[j]
                             : ((const float4*)Wt2)[j - 73728];
      ushort4 o; o.x = f2bf(v.x); o.y = f2bf(v.y); o.z = f2bf(v.z); o.w = f2bf(v.w);
      ((ushort4*)W2c)[j] = o;
    } else if (i < SWB) {
      int j = i - SW2;
      float4 v = ((const float4*)Wbil)[j];
      ushort4 o; o.x = f2bf(v.x); o.y = f2bf(v.y); o.z = f2bf(v.z); o.w = f2bf(v.w);
      ((ushort4*)Wb)[j] = o;
    } else if (i < SB2) {
      int j = i - SWB;
      ((float4*)b2cat)[j] = (j < 96) ? ((const float4*)bh2)[j]
                                     : ((const float4*)bt2)[j - 96];
    }
  } else if (blk < NBLK_W + NBLK_P) {
    const int w = (blk - NBLK_W) * 4 + (tid >> 6);
    const int lane = tid & 63;
    const int l = w / K1_;
    const int n = w - l * K1_;
    const float* wrow = (n < 768) ? (Wh1 + (size_t)n * K1_ + 768)
                                  : (Wt1 + (size_t)(n - 768) * K1_ + 768);
    const float  bb   = (n < 768) ? bh1[n] : bt1[n - 768];
    const float* ev = emb + (size_t)l * H_;
    float s = 0.f;
#pragma unroll
    for (int t = 0; t < 12; ++t) {
      int d = lane + 64 * t;
      s += ev[d] * wrow[d];
    }
#pragma unroll
    for (int off = 32; off; off >>= 1) s += __shfl_down(s, off);
    if (lane == 0) P[(size_t)l * K1_ + n] = s + bb;
  } else {
    const int be = blk - (NBLK_W + NBLK_P);
    if (tid < 192) {
      int b = be >> 7;
      int start = ent_start[be];
      const float4* s0 = (const float4*)(hs + ((size_t)b * W_ + start) * H_);
      float4 v = s0[tid];
      ushort4 o; o.x = f2bf(v.x); o.y = f2bf(v.y); o.z = f2bf(v.z); o.w = f2bf(v.w);
      ((ushort4*)(X + (size_t)be * H_))[tid] = o;
    }
  }
}

// ---------------------------------------------------------------------------
// bf16 MFMA GEMM, 128x128 tile, BK=64, 4 waves (2x2), double-buffered with
// COUNTED vmcnt pipeline (T4): per iter
//   stage(next) -> vmcnt(8) [waits prev iter's stage] -> barrier
//   -> ds_read+MFMA(cur) -> barrier
// Linear LDS + pre-swizzled source (XOR row&7). XCD-chunked block swizzle.
// ---------------------------------------------------------------------------
#define BM 128
#define BN 128

__global__ __launch_bounds__(256, 2) void gemm_bf16(
    const u16* __restrict__ A, int lda,
    const u16* __restrict__ Wt,              // [N][K] row-major
    const float* __restrict__ bias,
    u16* __restrict__ C, int ldc,
    int M, int N, int K, int do_relu, int half_n, int aoff,
    const float* __restrict__ rowBias,       // P [3][ldP] or null
    const int* __restrict__ rowLabel, int ldP)
{
  __shared__ char smem[2 * 32768];           // [buf][As 16KB | Bs 16KB]

  int bx, by;
  xcd_swizzle(bx, by);
  const int bn = bx * BN;
  const int bm = by * BM;

  const int tid  = threadIdx.x;
  const int wid  = tid >> 6;
  const int lane = tid & 63;
  const int wm = ((wid >> 1) & 1) * 64;
  const int wn = (wid & 1) * 64;

  const int a0 = (half_n && bn >= half_n) ? aoff : 0;

  const int srow = lane >> 3;
  const int sk8  = (lane & 7) ^ srow;
  const u16* gA = A  + (size_t)(bm + 32*wid + srow) * lda + a0 + 8*sk8;
  const u16* gB = Wt + (size_t)(bn + 32*wid + srow) * K  + 8*sk8;

  const int frow = lane & 15;
  const int fk8  = lane >> 4;

  f32x4 acc[4][4] = {};

  auto stage = [&](int buf, int k0) {
    char* As = smem + buf * 32768;
    char* Bs = As + 16384;
#pragma unroll
    for (int i = 0; i < 4; ++i) {
      gload_lds16(gA + k0 + (size_t)i * 8 * lda, As + (4*wid + i) * 1024);
      gload_lds16(gB + k0 + (size_t)i * 8 * K,   Bs + (4*wid + i) * 1024);
    }
  };

  const int nt = K / BKK;
  stage(0, 0);                                // 8 loads in flight

  for (int t = 0; t < nt; ++t) {
    const int cur = t & 1;
    if (t + 1 < nt) {
      stage(cur ^ 1, (t + 1) * BKK);          // +8 -> 16 in flight
      asm volatile("s_waitcnt vmcnt(8)" ::: "memory");  // stage(t) landed
    } else {
      asm volatile("s_waitcnt vmcnt(0)" ::: "memory");
    }
    __syncthreads();                          // all waves' stage(t) landed

    char* As = smem + cur * 32768;
    char* Bs = As + 16384;
#pragma unroll
    for (int kh = 0; kh < 2; ++kh) {
      bf16x8 a[4], b[4];
#pragma unroll
      for (int m = 0; m < 4; ++m) {
        const int row  = wm + m*16 + frow;
        const int slot = (kh*4 + fk8) ^ (row & 7);
        a[m] = *(const bf16x8*)(As + row*128 + slot*16);
      }
#pragma unroll
      for (int n = 0; n < 4; ++n) {
        const int row  = wn + n*16 + frow;
        const int slot = (kh*4 + fk8) ^ (row & 7);
        b[n] = *(const bf16x8*)(Bs + row*128 + slot*16);
      }
#pragma unroll
      for (int m = 0; m < 4; ++m)
#pragma unroll
        for (int n = 0; n < 4; ++n)
          acc[m][n] = __builtin_amdgcn_mfma_f32_16x16x32_bf16(
              a[m], b[n], acc[m][n], 0, 0, 0);
    }

    if (t + 1 < nt)
      __syncthreads();   // reads of cur done before t+1 stages into cur
  }

  int lbl[4][4];
  if (rowLabel) {
#pragma unroll
    for (int m = 0; m < 4; ++m)
#pragma unroll
      for (int r = 0; r < 4; ++r)
        lbl[m][r] = rowLabel[bm + wm + m*16 + fk8*4 + r];
  }

#pragma unroll
  for (int n = 0; n < 4; ++n) {
    const int col = bn + wn + n*16 + frow;
    const float bv = bias ? bias[col] : 0.f;
    float p0 = 0.f, p1 = 0.f, p2 = 0.f;
    if (rowLabel) {
      p0 = rowBias[col];
      p1 = rowBias[ldP + col];
      p2 = rowBias[2*ldP + col];
    }
#pragma unroll
    for (int m = 0; m < 4; ++m) {
#pragma unroll
      for (int r = 0; r < 4; ++r) {
        const int row = bm + wm + m*16 + fk8*4 + r;
        float v = acc[m][n][r] + bv;
        if (rowLabel) {
          int l = lbl[m][r];
          v += (l == 0) ? p0 : ((l == 1) ? p1 : p2);
        }
        if (do_relu) v = fmaxf(v, 0.f);
        C[(size_t)row * ldc + col] = f2bf(v);
      }
    }
  }
}

// ---------------------------------------------------------------------------
// Fused score-GEMM + CE, counted-vmcnt pipeline. One block per
// (doc-half bm, e2-quarter bn): 64x64 S-tile in LDS, then CE over the doc's
// relations landing in this tile; one atomic per block. No S in HBM.
// grid = 256, 4 waves, K=384.
// ---------------------------------------------------------------------------
__global__ __launch_bounds__(256, 2) void gemm_S_ce(
    const u16* __restrict__ Hcat, const u16* __restrict__ U,
    const float* __restrict__ linHT, const float* __restrict__ b_lin,
    const int* __restrict__ rel_head, const int* __restrict__ rel_tail,
    const int* __restrict__ rel_label, float* __restrict__ out)
{
  __shared__ char smem[2 * 16384];
  __shared__ float Sl[64][65];
  __shared__ float red[4];

  // bijective swizzle over 256 blocks (q=32, r=0)
  const int xcd = blockIdx.x & 7, idx = blockIdx.x >> 3;
  const int wgid = xcd * 32 + idx;
  const int bn = (wgid & 3) * 64;          // cols of [256]-wide (e2,o) space
  const int zz = wgid >> 2;
  const int z  = zz >> 1;
  const int bm = (zz & 1) * 64;            // e1 rows within doc

  const int tid  = threadIdx.x;
  const int wid  = tid >> 6;
  const int lane = tid & 63;
  const int srow = lane >> 3;
  const int sk8  = (lane & 7) ^ srow;

  auto stage = [&](int buf, int k0) {
    char* base = smem + buf * 16384;
#pragma unroll
    for (int i = 0; i < 4; ++i) {
      const int u = wid * 4 + i;
      if (u < 8) {
        const int row = z*128 + bm + u*8 + srow;
        gload_lds16(Hcat + (size_t)row * 768 + k0 + 8*sk8, base + u*1024);
      } else {
        const int row = bn + (u - 8)*8 + srow;
        gload_lds16(U + (size_t)z*98304 + (size_t)row * 384 + k0 + 8*sk8,
                    base + u*1024);
      }
    }
  };

  const int wm = (wid >> 1) * 32;
  const int wn = (wid & 1) * 32;
  const int frow = lane & 15;
  const int fk8  = lane >> 4;

  f32x4 acc[2][2] = {};

  stage(0, 0);                               // 4 loads in flight

  for (int t = 0; t < 6; ++t) {
    const int cur = t & 1;
    if (t + 1 < 6) {
      stage(cur ^ 1, (t + 1) * BKK);         // +4 -> 8 in flight
      asm volatile("s_waitcnt vmcnt(4)" ::: "memory");
    } else {
      asm volatile("s_waitcnt vmcnt(0)" ::: "memory");
    }
    __syncthreads();

    char* As = smem + cur * 16384;
    char* Bs = As + 8192;
#pragma unroll
    for (int kh = 0; kh < 2; ++kh) {
      bf16x8 a[2], b[2];
#pragma unroll
      for (int m = 0; m < 2; ++m) {
        const int row  = wm + m*16 + frow;
        const int slot = (kh*4 + fk8) ^ (row & 7);
        a[m] = *(const bf16x8*)(As + row*128 + slot*16);
      }
#pragma unroll
      for (int n = 0; n < 2; ++n) {
        const int row  = wn + n*16 + frow;
        const int slot = (kh*4 + fk8) ^ (row & 7);
        b[n] = *(const bf16x8*)(Bs + row*128 + slot*16);
      }
#pragma unroll
      for (int m = 0; m < 2; ++m)
#pragma unroll
        for (int n = 0; n < 2; ++n)
          acc[m][n] = __builtin_amdgcn_mfma_f32_16x16x32_bf16(
              a[m], b[n], acc[m][n], 0, 0, 0);
    }

    if (t + 1 < 6)
      __syncthreads();
  }

  // epilogue into LDS: o parity = frow&1 (bn, wn, n*16 even)
  const int o = frow & 1;
  const float blv = b_lin[o];
#pragma unroll
  for (int n = 0; n < 2; ++n) {
    const int lc = wn + n*16 + frow;
    const int e2 = (bn + lc) >> 1;
    const float lt = linHT[(size_t)(z*128 + e2) * 4 + 2 + o];
#pragma unroll
    for (int m = 0; m < 2; ++m) {
#pragma unroll
      for (int r = 0; r < 4; ++r) {
        const int lr = wm + m*16 + fk8*4 + r;
        const float lh = linHT[(size_t)(z*128 + bm + lr) * 4 + o];
        Sl[lr][lc] = acc[m][n][r] + lh + lt + blv;
      }
    }
  }
  __syncthreads();

  // CE over this tile's relations
  float nllsum = 0.f;
#pragma unroll
  for (int j = 0; j < 4; ++j) {
    const int i = z * 1024 + tid + 256 * j;
    const int rh = rel_head[i];
    const int rt = rel_tail[i];
    const int lab = rel_label[i];
    if ((unsigned)(rh - bm) < 64u && (unsigned)(rt*2 - bn) < 64u) {
      const float l0 = Sl[rh - bm][rt*2 - bn];
      const float l1 = Sl[rh - bm][rt*2 - bn + 1];
      const float mx = fmaxf(l0, l1);
      const float lse = mx + logf(expf(l0 - mx) + expf(l1 - mx));
      nllsum += lse - (lab == 0 ? l0 : l1);
    }
  }
#pragma unroll
  for (int off = 32; off; off >>= 1) nllsum += __shfl_down(nllsum, off);
  if (lane == 0) red[wid] = nllsum;
  __syncthreads();
  if (tid == 0)
    atomicAdd(out, (red[0] + red[1] + red[2] + red[3]) * (1.0f / R_));
}

// ---------------------------------------------------------------------------
// per-entity linear terms, grid-strided waves + ushort4 loads; zeroes out[0].
// ---------------------------------------------------------------------------
__global__ __launch_bounds__(256) void lin_parts_kernel(
    const u16* __restrict__ Hcat, const float* __restrict__ W_lin,
    float* __restrict__ linHT, float* __restrict__ out)
{
  if (blockIdx.x == 0 && threadIdx.x == 0) out[0] = 0.f;
  const int wave = blockIdx.x * 4 + (threadIdx.x >> 6);
  const int lane = threadIdx.x & 63;
  const int nwave = gridDim.x * 4;

  for (int be = wave; be < BE_; be += nwave) {
    const ushort4* src = (const ushort4*)(Hcat + (size_t)be * 768);
    float s0 = 0.f, s1 = 0.f, s2 = 0.f, s3 = 0.f;
#pragma unroll
    for (int rd = 0; rd < 3; ++rd) {
      const int idx4 = rd * 64 + lane;      // 0..191
      const int c = idx4 * 4;               // col 0..764
      ushort4 v4 = src[idx4];
      float4 w0 = *(const float4*)(W_lin + c);
      float4 w1 = *(const float4*)(W_lin + 768 + c);
      float d0 = bf2f(v4.x)*w0.x + bf2f(v4.y)*w0.y + bf2f(v4.z)*w0.z + bf2f(v4.w)*w0.w;
      float d1 = bf2f(v4.x)*w1.x + bf2f(v4.y)*w1.y + bf2f(v4.z)*w1.z + bf2f(v4.w)*w1.w;
      if (c < 384) { s0 += d0; s1 += d1; }
      else         { s2 += d0; s3 += d1; }
    }
#pragma unroll
    for (int off = 32; off; off >>= 1) {
      s0 += __shfl_down(s0, off);
      s1 += __shfl_down(s1, off);
      s2 += __shfl_down(s2, off);
      s3 += __shfl_down(s3, off);
    }
    if (lane == 0) {
      float4 v = {s0, s1, s2, s3};
      *(float4*)(linHT + (size_t)be * 4) = v;
    }
  }
}

// ---------------------------------------------------------------------------
extern "C" void kernel_launch(void* const* d_in, const int* in_sizes, int n_in,
                              void* d_out, int out_size, void* d_ws, size_t ws_size,
                              hipStream_t stream)
{
  const float* hs        = (const float*)d_in[0];
  const int*   rel_head  = (const int*)  d_in[1];
  const int*   rel_tail  = (const int*)  d_in[2];
  const int*   rel_label = (const int*)  d_in[3];
  const int*   ent_start = (const int*)  d_in[4];
  const int*   ent_label = (const int*)  d_in[6];
  const float* emb   = (const float*)d_in[7];
  const float* Wh1   = (const float*)d_in[8];
  const float* bh1   = (const float*)d_in[9];
  const float* Wh2   = (const float*)d_in[10];
  const float* bh2   = (const float*)d_in[11];
  const float* Wt1   = (const float*)d_in[12];
  const float* bt1   = (const float*)d_in[13];
  const float* Wt2   = (const float*)d_in[14];
  const float* bt2   = (const float*)d_in[15];
  const float* W_bil = (const float*)d_in[16];
  const float* W_lin = (const float*)d_in[17];
  const float* b_lin = (const float*)d_in[18];
  float* out = (float*)d_out;

  // workspace layout
  u16* X    = (u16*)d_ws;                 // 4096*768
  u16* H1   = X    + (size_t)BE_ * H_;    // 4096*1536
  u16* Hcat = H1   + (size_t)BE_ * K1_;   // 4096*768
  u16* U    = Hcat + (size_t)BE_ * H_;    // 4096*768
  u16* W1c  = U    + (size_t)BE_ * H_;    // 1536*768
  u16* W2c  = W1c  + (size_t)K1_ * H_;    // 768*768
  u16* Wb   = W2c  + (size_t)H_ * H_;     // 768*384
  float* b2cat = (float*)(Wb + (size_t)H_ * HH_);  // 768
  float* P     = b2cat + H_;                       // 3*1536
  float* linHT = P + 3*K1_;                        // 4096*4

  // 1) fused prep
  prep_all<<<dim3(NBLK_W + NBLK_P + NBLK_X), dim3(256), 0, stream>>>(
      Wh1, Wt1, Wh2, Wt2, W_bil, bh1, bt1, bh2, bt2, emb,
      hs, ent_start, W1c, W2c, Wb, b2cat, P, X);

  // 2) layer-1 GEMM: H1 = relu(X @ W1c^T + P[label]) [4096,1536], K=768
  gemm_bf16<<<dim3(K1_/BN, BE_/BM), dim3(256), 0, stream>>>(
      X, H_, W1c, (const float*)nullptr, H1, K1_, BE_, K1_, H_, 1, 0, 0,
      P, ent_label, K1_);

  // 3) layer-2 fused GEMM: Hcat = relu([H1h@Wh2^T ; H1t@Wt2^T] + b2cat) [4096,768]
  gemm_bf16<<<dim3(H_/BN, BE_/BM), dim3(256), 0, stream>>>(
      H1, K1_, W2c, b2cat, Hcat, H_, BE_, H_, H_, 1, HH_, H_,
      (const float*)nullptr, (const int*)nullptr, 0);

  // 4) per-entity linear terms (+ zero out)
  lin_parts_kernel<<<dim3(128), dim3(256), 0, stream>>>(Hcat, W_lin, linHT, out);

  // 5) bilinear hoist: U = Ht @ Wbil^T [4096,768], K=384
  gemm_bf16<<<dim3(H_/BN, BE_/BM), dim3(256), 0, stream>>>(
      Hcat + HH_, H_, Wb, (const float*)nullptr, U, H_, BE_, H_, HH_, 0, 0, 0,
      (const float*)nullptr, (const int*)nullptr, 0);

  // 6) fused score GEMM + CE (no S materialization)
  gemm_S_ce<<<dim3(256), dim3(256), 0, stream>>>(
      Hcat, U, linHT, b_lin, rel_head, rel_tail, rel_label, out);
}

// Round 8
// 68.388 us; speedup vs baseline: 1.4126x; 1.1200x over previous
//
#include <hip/hip_runtime.h>
#include <math.h>

typedef unsigned short u16;
typedef __bf16 bf16x8 __attribute__((ext_vector_type(8)));
typedef float f32x4 __attribute__((ext_vector_type(4)));

#define B_ 32
#define W_ 512
#define H_ 768
#define HH_ 384
#define E_ 128
#define R_ 1024
#define BE_ (B_*E_)     /* 4096 */
#define K1_ (2*H_)      /* 1536 */
#define BKK 64

__device__ __forceinline__ u16 f2bf(float f) {
  unsigned u = __float_as_uint(f);
  u = (u + 0x7fffu + ((u >> 16) & 1u)) >> 16;   // RNE
  return (u16)u;
}
__device__ __forceinline__ float bf2f(u16 u) {
  return __uint_as_float(((unsigned)u) << 16);
}

__device__ __forceinline__ void gload_lds16(const void* g, void* l) {
  __builtin_amdgcn_global_load_lds(
      (__attribute__((address_space(1))) void*)(g),
      (__attribute__((address_space(3))) void*)(l), 16, 0, 0);
}

// bijective XCD-chunked block swizzle (m204)
__device__ __forceinline__ void xcd_swizzle(int& bx, int& by) {
  const int nwg = gridDim.x * gridDim.y;
  int orig = blockIdx.y * gridDim.x + blockIdx.x;
  int q = nwg >> 3, r = nwg & 7;
  int xcd = orig & 7, idx = orig >> 3;
  int wgid = (xcd < r ? xcd * (q + 1) : r * (q + 1) + (xcd - r) * q) + idx;
  bx = wgid % gridDim.x;
  by = wgid / gridDim.x;
}

// ---------------------------------------------------------------------------
// Fused prep: (A) weight->bf16, (B) P table P[l,n]=emb[l].W1[n,768:]+b1[n],
// (C) entity token gather to bf16.
// ---------------------------------------------------------------------------
#define NBLK_W 2017
#define NBLK_P 1152
#define NBLK_X 4096

__global__ __launch_bounds__(256) void prep_all(
    const float* __restrict__ Wh1, const float* __restrict__ Wt1,
    const float* __restrict__ Wh2, const float* __restrict__ Wt2,
    const float* __restrict__ Wbil,
    const float* __restrict__ bh1, const float* __restrict__ bt1,
    const float* __restrict__ bh2, const float* __restrict__ bt2,
    const float* __restrict__ emb,
    const float* __restrict__ hs, const int* __restrict__ ent_start,
    u16* __restrict__ W1c, u16* __restrict__ W2c, u16* __restrict__ Wb,
    float* __restrict__ b2cat, float* __restrict__ P, u16* __restrict__ X)
{
  const int blk = blockIdx.x;
  const int tid = threadIdx.x;

  if (blk < NBLK_W) {
    const int i = blk * 256 + tid;
    const int SW1 = 294912;              // W1c: 1536 rows x 768 cols /4
    const int SW2 = SW1 + 147456;        // W2c: 768x768 /4
    const int SWB = SW2 + 73728;         // Wb:  768x384 /4
    const int SB2 = SWB + 192;           // b2cat: 768 /4
    if (i < SW1) {
      int row = i / 192, c = i % 192;
      const float4* src = (const float4*)((row < 768)
          ? (Wh1 + (size_t)row * K1_) : (Wt1 + (size_t)(row - 768) * K1_));
      float4 v = src[c];
      ushort4 o; o.x = f2bf(v.x); o.y = f2bf(v.y); o.z = f2bf(v.z); o.w = f2bf(v.w);
      ((ushort4*)W1c)[i] = o;
    } else if (i < SW2) {
      int j = i - SW1;
      float4 v = (j < 73728) ? ((const float4*)Wh2)[j]
                             : ((const float4*)Wt2)[j - 73728];
      ushort4 o; o.x = f2bf(v.x); o.y = f2bf(v.y); o.z = f2bf(v.z); o.w = f2bf(v.w);
      ((ushort4*)W2c)[j] = o;
    } else if (i < SWB) {
      int j = i - SW2;
      float4 v = ((const float4*)Wbil)[j];
      ushort4 o; o.x = f2bf(v.x); o.y = f2bf(v.y); o.z = f2bf(v.z); o.w = f2bf(v.w);
      ((ushort4*)Wb)[j] = o;
    } else if (i < SB2) {
      int j = i - SWB;
      ((float4*)b2cat)[j] = (j < 96) ? ((const float4*)bh2)[j]
                                     : ((const float4*)bt2)[j - 96];
    }
  } else if (blk < NBLK_W + NBLK_P) {
    const int w = (blk - NBLK_W) * 4 + (tid >> 6);
    const int lane = tid & 63;
    const int l = w / K1_;
    const int n = w - l * K1_;
    const float* wrow = (n < 768) ? (Wh1 + (size_t)n * K1_ + 768)
                                  : (Wt1 + (size_t)(n - 768) * K1_ + 768);
    const float  bb   = (n < 768) ? bh1[n] : bt1[n - 768];
    const float* ev = emb + (size_t)l * H_;
    float s = 0.f;
#pragma unroll
    for (int t = 0; t < 12; ++t) {
      int d = lane + 64 * t;
      s += ev[d] * wrow[d];
    }
#pragma unroll
    for (int off = 32; off; off >>= 1) s += __shfl_down(s, off);
    if (lane == 0) P[(size_t)l * K1_ + n] = s + bb;
  } else {
    const int be = blk - (NBLK_W + NBLK_P);
    if (tid < 192) {
      int b = be >> 7;
      int start = ent_start[be];
      const float4* s0 = (const float4*)(hs + ((size_t)b * W_ + start) * H_);
      float4 v = s0[tid];
      ushort4 o; o.x = f2bf(v.x); o.y = f2bf(v.y); o.z = f2bf(v.z); o.w = f2bf(v.w);
      ((ushort4*)(X + (size_t)be * H_))[tid] = o;
    }
  }
}

// ---------------------------------------------------------------------------
// bf16 MFMA GEMM, 128x128 tile, BK=64, 4 waves (2x2), double-buffered,
// COUNTED vmcnt + RAW s_barrier pipeline (T4; __syncthreads would drain
// vmcnt to 0 - the R7 mistake):
//   stage(next) -> vmcnt(8) -> s_barrier -> ds_read+MFMA(cur) -> s_barrier
// Linear LDS + pre-swizzled source (XOR row&7). XCD-chunked block swizzle.
// ---------------------------------------------------------------------------
#define BM 128
#define BN 128

__global__ __launch_bounds__(256, 2) void gemm_bf16(
    const u16* __restrict__ A, int lda,
    const u16* __restrict__ Wt,              // [N][K] row-major
    const float* __restrict__ bias,
    u16* __restrict__ C, int ldc,
    int M, int N, int K, int do_relu, int half_n, int aoff,
    const float* __restrict__ rowBias,       // P [3][ldP] or null
    const int* __restrict__ rowLabel, int ldP)
{
  __shared__ char smem[2 * 32768];           // [buf][As 16KB | Bs 16KB]

  int bx, by;
  xcd_swizzle(bx, by);
  const int bn = bx * BN;
  const int bm = by * BM;

  const int tid  = threadIdx.x;
  const int wid  = tid >> 6;
  const int lane = tid & 63;
  const int wm = ((wid >> 1) & 1) * 64;
  const int wn = (wid & 1) * 64;

  const int a0 = (half_n && bn >= half_n) ? aoff : 0;

  const int srow = lane >> 3;
  const int sk8  = (lane & 7) ^ srow;
  const u16* gA = A  + (size_t)(bm + 32*wid + srow) * lda + a0 + 8*sk8;
  const u16* gB = Wt + (size_t)(bn + 32*wid + srow) * K  + 8*sk8;

  const int frow = lane & 15;
  const int fk8  = lane >> 4;

  f32x4 acc[4][4] = {};

  auto stage = [&](int buf, int k0) {
    char* As = smem + buf * 32768;
    char* Bs = As + 16384;
#pragma unroll
    for (int i = 0; i < 4; ++i) {
      gload_lds16(gA + k0 + (size_t)i * 8 * lda, As + (4*wid + i) * 1024);
      gload_lds16(gB + k0 + (size_t)i * 8 * K,   Bs + (4*wid + i) * 1024);
    }
  };

  const int nt = K / BKK;
  stage(0, 0);                                // 8 loads in flight

  for (int t = 0; t < nt; ++t) {
    const int cur = t & 1;
    if (t + 1 < nt) {
      stage(cur ^ 1, (t + 1) * BKK);          // +8 -> 16 in flight
      asm volatile("s_waitcnt vmcnt(8)" ::: "memory");  // own stage(t) landed
    } else {
      asm volatile("s_waitcnt vmcnt(0)" ::: "memory");
    }
    __builtin_amdgcn_s_barrier();             // all waves' stage(t) landed

    char* As = smem + cur * 32768;
    char* Bs = As + 16384;
#pragma unroll
    for (int kh = 0; kh < 2; ++kh) {
      bf16x8 a[4], b[4];
#pragma unroll
      for (int m = 0; m < 4; ++m) {
        const int row  = wm + m*16 + frow;
        const int slot = (kh*4 + fk8) ^ (row & 7);
        a[m] = *(const bf16x8*)(As + row*128 + slot*16);
      }
#pragma unroll
      for (int n = 0; n < 4; ++n) {
        const int row  = wn + n*16 + frow;
        const int slot = (kh*4 + fk8) ^ (row & 7);
        b[n] = *(const bf16x8*)(Bs + row*128 + slot*16);
      }
#pragma unroll
      for (int m = 0; m < 4; ++m)
#pragma unroll
        for (int n = 0; n < 4; ++n)
          acc[m][n] = __builtin_amdgcn_mfma_f32_16x16x32_bf16(
              a[m], b[n], acc[m][n], 0, 0, 0);
    }

    if (t + 1 < nt)
      __builtin_amdgcn_s_barrier();   // reads of cur done before overwrite
  }

  int lbl[4][4];
  if (rowLabel) {
#pragma unroll
    for (int m = 0; m < 4; ++m)
#pragma unroll
      for (int r = 0; r < 4; ++r)
        lbl[m][r] = rowLabel[bm + wm + m*16 + fk8*4 + r];
  }

#pragma unroll
  for (int n = 0; n < 4; ++n) {
    const int col = bn + wn + n*16 + frow;
    const float bv = bias ? bias[col] : 0.f;
    float p0 = 0.f, p1 = 0.f, p2 = 0.f;
    if (rowLabel) {
      p0 = rowBias[col];
      p1 = rowBias[ldP + col];
      p2 = rowBias[2*ldP + col];
    }
#pragma unroll
    for (int m = 0; m < 4; ++m) {
#pragma unroll
      for (int r = 0; r < 4; ++r) {
        const int row = bm + wm + m*16 + fk8*4 + r;
        float v = acc[m][n][r] + bv;
        if (rowLabel) {
          int l = lbl[m][r];
          v += (l == 0) ? p0 : ((l == 1) ? p1 : p2);
        }
        if (do_relu) v = fmaxf(v, 0.f);
        C[(size_t)row * ldc + col] = f2bf(v);
      }
    }
  }
}

// ---------------------------------------------------------------------------
// Fused score-GEMM + CE, counted vmcnt + raw barrier pipeline. One block per
// (doc-half bm, e2-quarter bn): 64x64 S-tile in LDS, then CE over the doc's
// relations landing in this tile; one atomic per block. No S in HBM.
// grid = 256, 4 waves, K=384.
// ---------------------------------------------------------------------------
__global__ __launch_bounds__(256, 2) void gemm_S_ce(
    const u16* __restrict__ Hcat, const u16* __restrict__ U,
    const float* __restrict__ linHT, const float* __restrict__ b_lin,
    const int* __restrict__ rel_head, const int* __restrict__ rel_tail,
    const int* __restrict__ rel_label, float* __restrict__ out)
{
  __shared__ char smem[2 * 16384];
  __shared__ float Sl[64][65];
  __shared__ float red[4];

  // bijective swizzle over 256 blocks (q=32, r=0)
  const int xcd = blockIdx.x & 7, idx = blockIdx.x >> 3;
  const int wgid = xcd * 32 + idx;
  const int bn = (wgid & 3) * 64;          // cols of [256]-wide (e2,o) space
  const int zz = wgid >> 2;
  const int z  = zz >> 1;
  const int bm = (zz & 1) * 64;            // e1 rows within doc

  const int tid  = threadIdx.x;
  const int wid  = tid >> 6;
  const int lane = tid & 63;
  const int srow = lane >> 3;
  const int sk8  = (lane & 7) ^ srow;

  auto stage = [&](int buf, int k0) {
    char* base = smem + buf * 16384;
#pragma unroll
    for (int i = 0; i < 4; ++i) {
      const int u = wid * 4 + i;
      if (u < 8) {
        const int row = z*128 + bm + u*8 + srow;
        gload_lds16(Hcat + (size_t)row * 768 + k0 + 8*sk8, base + u*1024);
      } else {
        const int row = bn + (u - 8)*8 + srow;
        gload_lds16(U + (size_t)z*98304 + (size_t)row * 384 + k0 + 8*sk8,
                    base + u*1024);
      }
    }
  };

  const int wm = (wid >> 1) * 32;
  const int wn = (wid & 1) * 32;
  const int frow = lane & 15;
  const int fk8  = lane >> 4;

  f32x4 acc[2][2] = {};

  stage(0, 0);                               // 4 loads in flight

  for (int t = 0; t < 6; ++t) {
    const int cur = t & 1;
    if (t + 1 < 6) {
      stage(cur ^ 1, (t + 1) * BKK);         // +4 -> 8 in flight
      asm volatile("s_waitcnt vmcnt(4)" ::: "memory");
    } else {
      asm volatile("s_waitcnt vmcnt(0)" ::: "memory");
    }
    __builtin_amdgcn_s_barrier();

    char* As = smem + cur * 16384;
    char* Bs = As + 8192;
#pragma unroll
    for (int kh = 0; kh < 2; ++kh) {
      bf16x8 a[2], b[2];
#pragma unroll
      for (int m = 0; m < 2; ++m) {
        const int row  = wm + m*16 + frow;
        const int slot = (kh*4 + fk8) ^ (row & 7);
        a[m] = *(const bf16x8*)(As + row*128 + slot*16);
      }
#pragma unroll
      for (int n = 0; n < 2; ++n) {
        const int row  = wn + n*16 + frow;
        const int slot = (kh*4 + fk8) ^ (row & 7);
        b[n] = *(const bf16x8*)(Bs + row*128 + slot*16);
      }
#pragma unroll
      for (int m = 0; m < 2; ++m)
#pragma unroll
        for (int n = 0; n < 2; ++n)
          acc[m][n] = __builtin_amdgcn_mfma_f32_16x16x32_bf16(
              a[m], b[n], acc[m][n], 0, 0, 0);
    }

    if (t + 1 < 6)
      __builtin_amdgcn_s_barrier();
  }

  // epilogue into LDS: o parity = frow&1 (bn, wn, n*16 even)
  const int o = frow & 1;
  const float blv = b_lin[o];
#pragma unroll
  for (int n = 0; n < 2; ++n) {
    const int lc = wn + n*16 + frow;
    const int e2 = (bn + lc) >> 1;
    const float lt = linHT[(size_t)(z*128 + e2) * 4 + 2 + o];
#pragma unroll
    for (int m = 0; m < 2; ++m) {
#pragma unroll
      for (int r = 0; r < 4; ++r) {
        const int lr = wm + m*16 + fk8*4 + r;
        const float lh = linHT[(size_t)(z*128 + bm + lr) * 4 + o];
        Sl[lr][lc] = acc[m][n][r] + lh + lt + blv;
      }
    }
  }
  __syncthreads();

  // CE over this tile's relations
  float nllsum = 0.f;
#pragma unroll
  for (int j = 0; j < 4; ++j) {
    const int i = z * 1024 + tid + 256 * j;
    const int rh = rel_head[i];
    const int rt = rel_tail[i];
    const int lab = rel_label[i];
    if ((unsigned)(rh - bm) < 64u && (unsigned)(rt*2 - bn) < 64u) {
      const float l0 = Sl[rh - bm][rt*2 - bn];
      const float l1 = Sl[rh - bm][rt*2 - bn + 1];
      const float mx = fmaxf(l0, l1);
      const float lse = mx + logf(expf(l0 - mx) + expf(l1 - mx));
      nllsum += lse - (lab == 0 ? l0 : l1);
    }
  }
#pragma unroll
  for (int off = 32; off; off >>= 1) nllsum += __shfl_down(nllsum, off);
  if (lane == 0) red[wid] = nllsum;
  __syncthreads();
  if (tid == 0)
    atomicAdd(out, (red[0] + red[1] + red[2] + red[3]) * (1.0f / R_));
}

// ---------------------------------------------------------------------------
// per-entity linear terms, grid-strided waves + ushort4 loads; zeroes out[0].
// ---------------------------------------------------------------------------
__global__ __launch_bounds__(256) void lin_parts_kernel(
    const u16* __restrict__ Hcat, const float* __restrict__ W_lin,
    float* __restrict__ linHT, float* __restrict__ out)
{
  if (blockIdx.x == 0 && threadIdx.x == 0) out[0] = 0.f;
  const int wave = blockIdx.x * 4 + (threadIdx.x >> 6);
  const int lane = threadIdx.x & 63;
  const int nwave = gridDim.x * 4;

  for (int be = wave; be < BE_; be += nwave) {
    const ushort4* src = (const ushort4*)(Hcat + (size_t)be * 768);
    float s0 = 0.f, s1 = 0.f, s2 = 0.f, s3 = 0.f;
#pragma unroll
    for (int rd = 0; rd < 3; ++rd) {
      const int idx4 = rd * 64 + lane;      // 0..191
      const int c = idx4 * 4;               // col 0..764
      ushort4 v4 = src[idx4];
      float4 w0 = *(const float4*)(W_lin + c);
      float4 w1 = *(const float4*)(W_lin + 768 + c);
      float d0 = bf2f(v4.x)*w0.x + bf2f(v4.y)*w0.y + bf2f(v4.z)*w0.z + bf2f(v4.w)*w0.w;
      float d1 = bf2f(v4.x)*w1.x + bf2f(v4.y)*w1.y + bf2f(v4.z)*w1.z + bf2f(v4.w)*w1.w;
      if (c < 384) { s0 += d0; s1 += d1; }
      else         { s2 += d0; s3 += d1; }
    }
#pragma unroll
    for (int off = 32; off; off >>= 1) {
      s0 += __shfl_down(s0, off);
      s1 += __shfl_down(s1, off);
      s2 += __shfl_down(s2, off);
      s3 += __shfl_down(s3, off);
    }
    if (lane == 0) {
      float4 v = {s0, s1, s2, s3};
      *(float4*)(linHT + (size_t)be * 4) = v;
    }
  }
}

// ---------------------------------------------------------------------------
extern "C" void kernel_launch(void* const* d_in, const int* in_sizes, int n_in,
                              void* d_out, int out_size, void* d_ws, size_t ws_size,
                              hipStream_t stream)
{
  const float* hs        = (const float*)d_in[0];
  const int*   rel_head  = (const int*)  d_in[1];
  const int*   rel_tail  = (const int*)  d_in[2];
  const int*   rel_label = (const int*)  d_in[3];
  const int*   ent_start = (const int*)  d_in[4];
  const int*   ent_label = (const int*)  d_in[6];
  const float* emb   = (const float*)d_in[7];
  const float* Wh1   = (const float*)d_in[8];
  const float* bh1   = (const float*)d_in[9];
  const float* Wh2   = (const float*)d_in[10];
  const float* bh2   = (const float*)d_in[11];
  const float* Wt1   = (const float*)d_in[12];
  const float* bt1   = (const float*)d_in[13];
  const float* Wt2   = (const float*)d_in[14];
  const float* bt2   = (const float*)d_in[15];
  const float* W_bil = (const float*)d_in[16];
  const float* W_lin = (const float*)d_in[17];
  const float* b_lin = (const float*)d_in[18];
  float* out = (float*)d_out;

  // workspace layout
  u16* X    = (u16*)d_ws;                 // 4096*768
  u16* H1   = X    + (size_t)BE_ * H_;    // 4096*1536
  u16* Hcat = H1   + (size_t)BE_ * K1_;   // 4096*768
  u16* U    = Hcat + (size_t)BE_ * H_;    // 4096*768
  u16* W1c  = U    + (size_t)BE_ * H_;    // 1536*768
  u16* W2c  = W1c  + (size_t)K1_ * H_;    // 768*768
  u16* Wb   = W2c  + (size_t)H_ * H_;     // 768*384
  float* b2cat = (float*)(Wb + (size_t)H_ * HH_);  // 768
  float* P     = b2cat + H_;                       // 3*1536
  float* linHT = P + 3*K1_;                        // 4096*4

  // 1) fused prep
  prep_all<<<dim3(NBLK_W + NBLK_P + NBLK_X), dim3(256), 0, stream>>>(
      Wh1, Wt1, Wh2, Wt2, W_bil, bh1, bt1, bh2, bt2, emb,
      hs, ent_start, W1c, W2c, Wb, b2cat, P, X);

  // 2) layer-1 GEMM: H1 = relu(X @ W1c^T + P[label]) [4096,1536], K=768
  gemm_bf16<<<dim3(K1_/BN, BE_/BM), dim3(256), 0, stream>>>(
      X, H_, W1c, (const float*)nullptr, H1, K1_, BE_, K1_, H_, 1, 0, 0,
      P, ent_label, K1_);

  // 3) layer-2 fused GEMM: Hcat = relu([H1h@Wh2^T ; H1t@Wt2^T] + b2cat) [4096,768]
  gemm_bf16<<<dim3(H_/BN, BE_/BM), dim3(256), 0, stream>>>(
      H1, K1_, W2c, b2cat, Hcat, H_, BE_, H_, H_, 1, HH_, H_,
      (const float*)nullptr, (const int*)nullptr, 0);

  // 4) per-entity linear terms (+ zero out)
  lin_parts_kernel<<<dim3(128), dim3(256), 0, stream>>>(Hcat, W_lin, linHT, out);

  // 5) bilinear hoist: U = Ht @ Wbil^T [4096,768], K=384
  gemm_bf16<<<dim3(H_/BN, BE_/BM), dim3(256), 0, stream>>>(
      Hcat + HH_, H_, Wb, (const float*)nullptr, U, H_, BE_, H_, HH_, 0, 0, 0,
      (const float*)nullptr, (const int*)nullptr, 0);

  // 6) fused score GEMM + CE (no S materialization)
  gemm_S_ce<<<dim3(256), dim3(256), 0, stream>>>(
      Hcat, U, linHT, b_lin, rel_head, rel_tail, rel_label, out);
}